// Round 10
// baseline (634.799 us; speedup 1.0000x reference)
//
#include <hip/hip_runtime.h>

#define NA 50000
#define NT 25000
#define EAA 800000
#define EAT 400000
#define ETA 400000
#define NSEG 125000          // NA + NA + NT rows: [aa | ta | at]
#define TOTAL_E 1600000
#define NB 245               // coarse buckets of 512 rows
#define NBLK1 196            // pass-1 blocks
#define CHUNK 8192           // edges per pass-1 block
#define AGB 391              // conv1/out agent blocks (128 rows each)
#define TGB 196              // conv1/out target blocks

// ---- workspace layout (4-byte element offsets) ----
#define O_HIST    0          // int[48020]: hist[bucket][block] -> scanned bases
#define O_ATSRC   48064      // int[50000]
#define O_TASRC   98064      // int[25000]
#define O_RO      123072     // int[125001]: CSR row offsets
#define O_CAA     248128     // float[50000]: rsqrt(indeg_aa+1)
#define O_CTAD    298128     // float[50000]
#define O_CATD    348128     // float[25000]
#define O_CATS    373128     // float[50000]
#define O_CTAS    423128     // float[25000]
#define O_U       448128     // float[512]
#define O_P       448640     // float[100000]
#define O_Q       548640     // float[100000]
#define O_R       648640     // float[50000]
#define O_REC     698640     // int[1600000]: bucket-sorted records (row_local<<16)|src
#define O_REC2    2298640    // int[1600000]: row-sorted records

// ---------- pass 1a: per-block coarse histogram (LDS) + fused src-degree atomics ----------
__global__ void __launch_bounds__(256)
p1_hist_kernel(const int* __restrict__ dst_aa, const int* __restrict__ dst_ta,
               const int* __restrict__ dst_at, const int* __restrict__ src_ta,
               const int* __restrict__ src_at, int* __restrict__ wi) {
    __shared__ int h[NB];
    for (int i = threadIdx.x; i < NB; i += 256) h[i] = 0;
    __syncthreads();
    int b = blockIdx.x;
    int t0 = b * CHUNK, t1 = min(t0 + CHUNK, TOTAL_E);
    for (int t = t0 + threadIdx.x; t < t1; t += 256) {
        int row;
        if (t < EAA) {
            row = dst_aa[t];
        } else if (t < EAA + ETA) {
            int u = t - EAA;
            row = NA + dst_ta[u];
            atomicAdd(&wi[O_TASRC + src_ta[u]], 1);
        } else {
            int u = t - EAA - ETA;
            row = 2 * NA + dst_at[u];
            atomicAdd(&wi[O_ATSRC + src_at[u]], 1);
        }
        atomicAdd(&h[row >> 9], 1);
    }
    __syncthreads();
    for (int i = threadIdx.x; i < NB; i += 256) wi[O_HIST + i * NBLK1 + b] = h[i];
}

// ---------- aux: block 0 = hist scan; blocks 1..74 = src coefs; block 75 = U fuse ----------
__global__ void __launch_bounds__(1024)
aux_kernel(int* __restrict__ wi, float* __restrict__ wf,
           const float* __restrict__ W2_aa, const float* __restrict__ W2_ta,
           const float* __restrict__ W2_at, const float* __restrict__ b2_aa,
           const float* __restrict__ b2_ta, const float* __restrict__ b2_at,
           const float* __restrict__ Wp_a, const float* __restrict__ bp_a,
           const float* __restrict__ Wp_t, const float* __restrict__ bp_t) {
    if (blockIdx.x == 0) {
        __shared__ int wsum[16];
        __shared__ int sCarry;
        int* h = wi + O_HIST;
        int tid = threadIdx.x, lane = tid & 63, wid = tid >> 6;
        if (tid == 0) sCarry = 0;
        __syncthreads();
        const int N2 = NB * NBLK1;
        for (int base = 0; base < N2; base += 1024) {
            int idx = base + tid;
            int v = (idx < N2) ? h[idx] : 0;
            int x = v;
#pragma unroll
            for (int off = 1; off < 64; off <<= 1) {
                int y = __shfl_up(x, off, 64);
                if (lane >= off) x += y;
            }
            if (lane == 63) wsum[wid] = x;
            __syncthreads();
            int wpre = 0, tot = 0;
            for (int w = 0; w < 16; ++w) {
                int s = wsum[w];
                if (w < wid) wpre += s;
                tot += s;
            }
            int excl = x - v + wpre + sCarry;
            if (idx < N2) h[idx] = excl;
            __syncthreads();
            if (tid == 0) sCarry += tot;
            __syncthreads();
        }
    } else if (blockIdx.x <= 74) {
        int t = (blockIdx.x - 1) * 1024 + threadIdx.x;
        if (t < 50000) {
            int d = wi[O_ATSRC + t];
            wf[O_CATS + t] = d > 0 ? rsqrtf((float)d) : 0.0f;
        } else if (t < 75000) {
            int i = t - 50000; int d = wi[O_TASRC + i];
            wf[O_CTAS + i] = d > 0 ? rsqrtf((float)d) : 0.0f;
        }
    } else {
        float* U = wf + O_U;
        int t = threadIdx.x;
        if (t < 128) {
            int k = t >> 1, j = t & 1;
            float a = 0.f;
            for (int f = 0; f < 64; ++f) a = fmaf(W2_aa[k * 64 + f], Wp_a[f * 2 + j], a);
            U[t] = a;
        } else if (t < 256) {
            int u = t - 128; int k = u >> 1, j = u & 1;
            float a = 0.f;
            for (int f = 0; f < 64; ++f) a = fmaf(W2_ta[k * 64 + f], Wp_a[f * 2 + j], a);
            U[128 + u] = a;
        } else if (t < 384) {
            int u = t - 256; int k = u >> 1, j = u & 1;
            float a = 0.f;
            for (int f = 0; f < 64; ++f) a = fmaf(W2_at[k * 64 + f], Wp_t[f * 2 + j], a);
            U[256 + u] = a;
        } else if (t < 386) {
            int j = t - 384;
            float a = bp_a[j];
            for (int f = 0; f < 64; ++f) a = fmaf(b2_aa[f] + b2_ta[f], Wp_a[f * 2 + j], a);
            U[384 + j] = a;
        } else if (t < 388) {
            int j = t - 386;
            float a = bp_t[j];
            for (int f = 0; f < 64; ++f) a = fmaf(b2_at[f], Wp_t[f * 2 + j], a);
            U[386 + j] = a;
        }
    }
}

// ---------- pass 1c: scatter packed records via LDS cursors (block-exclusive runs) ----------
__global__ void __launch_bounds__(256)
p1_scatter_kernel(const int* __restrict__ src_aa, const int* __restrict__ dst_aa,
                  const int* __restrict__ src_ta, const int* __restrict__ dst_ta,
                  const int* __restrict__ src_at, const int* __restrict__ dst_at,
                  const int* __restrict__ hist_g, int* __restrict__ rec) {
    __shared__ int cur[NB];
    int b = blockIdx.x;
    for (int i = threadIdx.x; i < NB; i += 256) cur[i] = hist_g[i * NBLK1 + b];
    __syncthreads();
    int t0 = b * CHUNK, t1 = min(t0 + CHUNK, TOTAL_E);
    for (int t = t0 + threadIdx.x; t < t1; t += 256) {
        int row, s;
        if (t < EAA) { row = dst_aa[t]; s = src_aa[t]; }
        else if (t < EAA + ETA) { int u = t - EAA; row = NA + dst_ta[u]; s = src_ta[u]; }
        else { int u = t - EAA - ETA; row = 2 * NA + dst_at[u]; s = src_at[u]; }
        int pos = atomicAdd(&cur[row >> 9], 1);
        rec[pos] = ((row & 511) << 16) | s;
    }
}

// ---------- pass 2: per-bucket degree count + LDS scan -> ro + dst coefs + ROW-SORTED records ----------
__global__ void __launch_bounds__(256)
p2_kernel(const int* __restrict__ hist_g, const int* __restrict__ rec,
          int* __restrict__ ro, float* __restrict__ caa, float* __restrict__ ctad,
          float* __restrict__ catd, int* __restrict__ rec2) {
    __shared__ int deg[512];
    __shared__ int rb[512];
    __shared__ int wsum[4];
    int k = blockIdx.x, tid = threadIdx.x, lane = tid & 63, wid = tid >> 6;
    int e0 = hist_g[k * NBLK1];
    int e1 = (k + 1 < NB) ? hist_g[(k + 1) * NBLK1] : TOTAL_E;
    deg[tid] = 0; deg[tid + 256] = 0;
    __syncthreads();
    for (int j = e0 + tid; j < e1; j += 256) atomicAdd(&deg[rec[j] >> 16], 1);
    __syncthreads();
    int d0 = deg[2 * tid], d1 = deg[2 * tid + 1];
    int v = d0 + d1;
    int x = v;
#pragma unroll
    for (int off = 1; off < 64; off <<= 1) {
        int y = __shfl_up(x, off, 64);
        if (lane >= off) x += y;
    }
    if (lane == 63) wsum[wid] = x;
    __syncthreads();
    int wpre = 0;
    for (int w = 0; w < wid; ++w) wpre += wsum[w];
    int pexcl = x - v + wpre;
    rb[2 * tid] = e0 + pexcl;
    rb[2 * tid + 1] = e0 + pexcl + d0;
    __syncthreads();
    for (int i = tid; i < 512; i += 256) {
        int g = k * 512 + i;
        if (g < NSEG) {
            ro[g] = rb[i];
            int d = deg[i];
            if (g < NA) caa[g] = rsqrtf((float)d + 1.0f);
            else if (g < 2 * NA) ctad[g - NA] = d > 0 ? rsqrtf((float)d) : 0.0f;
            else catd[g - 2 * NA] = d > 0 ? rsqrtf((float)d) : 0.0f;
        }
    }
    if (k == NB - 1 && tid == 0) ro[NSEG] = TOTAL_E;
    __syncthreads();
    // scatter records into row-sorted order within this bucket's exclusive window
    for (int j = e0 + tid; j < e1; j += 256) {
        int rc = rec[j];
        int pos = atomicAdd(&rb[rc >> 16], 1);
        rec2[pos] = rc;
    }
}

// ---------- conv1: edge-parallel LDS aggregation + dense matvec, 128 rows/block ----------
__global__ void __launch_bounds__(256)
conv1_all_kernel(const float* __restrict__ x_a, const float* __restrict__ x_t,
                 const int* __restrict__ ro, const int* __restrict__ rec,
                 const float* __restrict__ c_aa, const float* __restrict__ c_ta_d,
                 const float* __restrict__ c_ta_s, const float* __restrict__ c_at_s,
                 const float* __restrict__ c_at_d,
                 const float* __restrict__ W_aa, const float* __restrict__ b_aa,
                 const float* __restrict__ W_ta, const float* __restrict__ b_ta,
                 const float* __restrict__ W_at, const float* __restrict__ b_at,
                 const float* __restrict__ U,
                 float* __restrict__ p, float* __restrict__ q, float* __restrict__ r) {
    __shared__ float accA[128 * 33];
    __shared__ float accT[128 * 33];
    __shared__ float sWt0[2048];     // W^T [col][k]
    __shared__ float sWt1[2048];
    __shared__ float sBias[64];
    __shared__ float sUa[128];
    __shared__ float sUb[128];
    int tid = threadIdx.x, lane = tid & 63, wave = tid >> 6;
    int e8 = lane >> 3, k4 = lane & 7;

    if (blockIdx.x < AGB) {
        // =============== agents ===============
        int r0 = blockIdx.x * 128;
        int nr = min(128, NA - r0);
        for (int idx = tid; idx < 2048; idx += 256) {
            int c = idx >> 5, k = idx & 31;
            sWt0[idx] = W_aa[k * 64 + c];
            sWt1[idx] = W_ta[k * 64 + c];
        }
        if (tid < 64) sBias[tid] = b_aa[tid] + b_ta[tid];
        if (tid < 128) { sUa[tid] = U[tid]; sUb[tid] = U[256 + tid]; }
        for (int idx = tid; idx < 128 * 33; idx += 256) { accA[idx] = 0.f; accT[idx] = 0.f; }
        __syncthreads();

        // aa edges (row-sorted range is exact for this window)
        int j0 = ro[r0], j1 = ro[r0 + nr];
        int base = r0 & 511;
        for (int g = wave; g * 8 < j1 - j0; g += 4) {
            int j = j0 + g * 8 + e8;
            if (j < j1) {
                int rc = rec[j];
                int s = rc & 0xFFFF;
                int rl = ((rc >> 16) - base) & 511;
                float w = c_aa[s];
                float4 xv = *(const float4*)(x_a + (size_t)s * 32 + k4 * 4);
                float* a = &accA[rl * 33 + k4 * 4];
                atomicAdd(a + 0, xv.x * w);
                atomicAdd(a + 1, xv.y * w);
                atomicAdd(a + 2, xv.z * w);
                atomicAdd(a + 3, xv.w * w);
            }
        }
        // self-loop terms
        for (int idx = tid; idx < nr * 32; idx += 256) {
            int row = idx >> 5, k = idx & 31;
            int i = r0 + row;
            atomicAdd(&accA[row * 33 + k], x_a[(size_t)i * 32 + k] * c_aa[i]);
        }
        // ta edges
        int t0 = ro[NA + r0], t1 = ro[NA + r0 + nr];
        int baseT = (NA + r0) & 511;
        for (int g = wave; g * 8 < t1 - t0; g += 4) {
            int j = t0 + g * 8 + e8;
            if (j < t1) {
                int rc = rec[j];
                int s = rc & 0xFFFF;
                int rl = ((rc >> 16) - baseT) & 511;
                float w = c_ta_s[s];
                float4 xv = *(const float4*)(x_t + (size_t)s * 32 + k4 * 4);
                float* a = &accT[rl * 33 + k4 * 4];
                atomicAdd(a + 0, xv.x * w);
                atomicAdd(a + 1, xv.y * w);
                atomicAdd(a + 2, xv.z * w);
                atomicAdd(a + 3, xv.w * w);
            }
        }
        __syncthreads();

        // matvec: wave handles 32 rows; lane pair per row, halves split cols
        int row = wave * 32 + (lane >> 1);
        int half = lane & 1;
        if (row < nr) {
            int i = r0 + row;
            float aA[32], aT[32];
#pragma unroll
            for (int k = 0; k < 32; ++k) {
                aA[k] = accA[row * 33 + k];
                aT[k] = accT[row * 33 + k];
            }
            float ci = c_aa[i], ct = c_ta_d[i];
            float p0 = 0.f, p1 = 0.f, q0 = 0.f, q1 = 0.f;
            for (int cc = 0; cc < 32; ++cc) {
                int col = half * 32 + cc;
                float hA = 0.f, hT = 0.f;
#pragma unroll
                for (int kc = 0; kc < 8; ++kc) {
                    float4 w4 = *(const float4*)&sWt0[col * 32 + kc * 4];
                    hA = fmaf(aA[kc * 4 + 0], w4.x, hA);
                    hA = fmaf(aA[kc * 4 + 1], w4.y, hA);
                    hA = fmaf(aA[kc * 4 + 2], w4.z, hA);
                    hA = fmaf(aA[kc * 4 + 3], w4.w, hA);
                    float4 v4 = *(const float4*)&sWt1[col * 32 + kc * 4];
                    hT = fmaf(aT[kc * 4 + 0], v4.x, hT);
                    hT = fmaf(aT[kc * 4 + 1], v4.y, hT);
                    hT = fmaf(aT[kc * 4 + 2], v4.z, hT);
                    hT = fmaf(aT[kc * 4 + 3], v4.w, hT);
                }
                float h = fmaxf(sBias[col] + ci * hA + ct * hT, 0.f);
                p0 = fmaf(h, sUa[col * 2], p0);
                p1 = fmaf(h, sUa[col * 2 + 1], p1);
                q0 = fmaf(h, sUb[col * 2], q0);
                q1 = fmaf(h, sUb[col * 2 + 1], q1);
            }
            p0 += __shfl_xor(p0, 1, 64);
            p1 += __shfl_xor(p1, 1, 64);
            q0 += __shfl_xor(q0, 1, 64);
            q1 += __shfl_xor(q1, 1, 64);
            if (half == 0) {
                float cq = c_at_s[i];
                *(float2*)&p[i * 2] = make_float2(p0 * ci, p1 * ci);
                *(float2*)&q[i * 2] = make_float2(q0 * cq, q1 * cq);
            }
        }
    } else {
        // =============== targets ===============
        int r0 = (blockIdx.x - AGB) * 128;
        int nr = min(128, NT - r0);
        for (int idx = tid; idx < 2048; idx += 256) {
            int c = idx >> 5, k = idx & 31;
            sWt0[idx] = W_at[k * 64 + c];
        }
        if (tid < 64) sBias[tid] = b_at[tid];
        if (tid < 128) sUa[tid] = U[128 + tid];
        for (int idx = tid; idx < 128 * 33; idx += 256) accA[idx] = 0.f;
        __syncthreads();

        int j0 = ro[2 * NA + r0], j1 = ro[2 * NA + r0 + nr];
        int base = (2 * NA + r0) & 511;
        for (int g = wave; g * 8 < j1 - j0; g += 4) {
            int j = j0 + g * 8 + e8;
            if (j < j1) {
                int rc = rec[j];
                int s = rc & 0xFFFF;
                int rl = ((rc >> 16) - base) & 511;
                float w = c_at_s[s];
                float4 xv = *(const float4*)(x_a + (size_t)s * 32 + k4 * 4);
                float* a = &accA[rl * 33 + k4 * 4];
                atomicAdd(a + 0, xv.x * w);
                atomicAdd(a + 1, xv.y * w);
                atomicAdd(a + 2, xv.z * w);
                atomicAdd(a + 3, xv.w * w);
            }
        }
        __syncthreads();

        int row = wave * 32 + (lane >> 1);
        int half = lane & 1;
        if (row < nr) {
            int i = r0 + row;
            float aA[32];
#pragma unroll
            for (int k = 0; k < 32; ++k) aA[k] = accA[row * 33 + k];
            float cd = c_at_d[i];
            float r0v = 0.f, r1v = 0.f;
            for (int cc = 0; cc < 32; ++cc) {
                int col = half * 32 + cc;
                float hA = 0.f;
#pragma unroll
                for (int kc = 0; kc < 8; ++kc) {
                    float4 w4 = *(const float4*)&sWt0[col * 32 + kc * 4];
                    hA = fmaf(aA[kc * 4 + 0], w4.x, hA);
                    hA = fmaf(aA[kc * 4 + 1], w4.y, hA);
                    hA = fmaf(aA[kc * 4 + 2], w4.z, hA);
                    hA = fmaf(aA[kc * 4 + 3], w4.w, hA);
                }
                float h = fmaxf(sBias[col] + cd * hA, 0.f);
                r0v = fmaf(h, sUa[col * 2], r0v);
                r1v = fmaf(h, sUa[col * 2 + 1], r1v);
            }
            r0v += __shfl_xor(r0v, 1, 64);
            r1v += __shfl_xor(r1v, 1, 64);
            if (half == 0) {
                float cr = c_ta_s[i];
                *(float2*)&r[i * 2] = make_float2(r0v * cr, r1v * cr);
            }
        }
    }
}

// ---------- conv2+proj: edge-parallel LDS accumulation, 128 rows/block ----------
__global__ void __launch_bounds__(256)
out_all_kernel(const float* __restrict__ p, const float* __restrict__ q,
               const float* __restrict__ r, const int* __restrict__ ro,
               const int* __restrict__ rec,
               const float* __restrict__ c_aa, const float* __restrict__ c_ta_d,
               const float* __restrict__ c_at_d, const float* __restrict__ U,
               float* __restrict__ out) {
    __shared__ float accP[128 * 3];
    __shared__ float accR[128 * 3];
    int tid = threadIdx.x, lane = tid & 63, wave = tid >> 6;
    int e32 = lane >> 1, jj = lane & 1;

    if (blockIdx.x < AGB) {
        int r0 = blockIdx.x * 128;
        int nr = min(128, NA - r0);
        for (int idx = tid; idx < 384; idx += 256) { accP[idx] = 0.f; accR[idx] = 0.f; }
        __syncthreads();
        int j0 = ro[r0], j1 = ro[r0 + nr];
        int base = r0 & 511;
        for (int g = wave; g * 32 < j1 - j0; g += 4) {
            int j = j0 + g * 32 + e32;
            if (j < j1) {
                int rc = rec[j];
                int s = rc & 0xFFFF;
                int rl = ((rc >> 16) - base) & 511;
                atomicAdd(&accP[rl * 3 + jj], p[s * 2 + jj]);
            }
        }
        int t0 = ro[NA + r0], t1 = ro[NA + r0 + nr];
        int baseT = (NA + r0) & 511;
        for (int g = wave; g * 32 < t1 - t0; g += 4) {
            int j = t0 + g * 32 + e32;
            if (j < t1) {
                int rc = rec[j];
                int s = rc & 0xFFFF;
                int rl = ((rc >> 16) - baseT) & 511;
                atomicAdd(&accR[rl * 3 + jj], r[s * 2 + jj]);
            }
        }
        __syncthreads();
        for (int idx = tid; idx < nr * 2; idx += 256) {
            int row = idx >> 1, jc = idx & 1;
            int i = r0 + row;
            float ci = c_aa[i];
            out[i * 2 + jc] = U[384 + jc] + (accP[row * 3 + jc] + p[i * 2 + jc]) * ci
                            + accR[row * 3 + jc] * c_ta_d[i];
        }
    } else {
        int r0 = (blockIdx.x - AGB) * 128;
        int nr = min(128, NT - r0);
        for (int idx = tid; idx < 384; idx += 256) accP[idx] = 0.f;
        __syncthreads();
        int j0 = ro[2 * NA + r0], j1 = ro[2 * NA + r0 + nr];
        int base = (2 * NA + r0) & 511;
        for (int g = wave; g * 32 < j1 - j0; g += 4) {
            int j = j0 + g * 32 + e32;
            if (j < j1) {
                int rc = rec[j];
                int s = rc & 0xFFFF;
                int rl = ((rc >> 16) - base) & 511;
                atomicAdd(&accP[rl * 3 + jj], q[s * 2 + jj]);
            }
        }
        __syncthreads();
        for (int idx = tid; idx < nr * 2; idx += 256) {
            int row = idx >> 1, jc = idx & 1;
            int i = r0 + row;
            out[NA * 2 + i * 2 + jc] = U[386 + jc] + accP[row * 3 + jc] * c_at_d[i];
        }
    }
}

extern "C" void kernel_launch(void* const* d_in, const int* in_sizes, int n_in,
                              void* d_out, int out_size, void* d_ws, size_t ws_size,
                              hipStream_t stream) {
    const float* x_a   = (const float*)d_in[1];
    const float* x_t   = (const float*)d_in[2];
    const int* src_aa  = (const int*)d_in[3];
    const int* dst_aa  = (const int*)d_in[4];
    const int* src_at  = (const int*)d_in[5];
    const int* dst_at  = (const int*)d_in[6];
    const int* src_ta  = (const int*)d_in[7];
    const int* dst_ta  = (const int*)d_in[8];
    const float* W1_aa = (const float*)d_in[9];
    const float* b1_aa = (const float*)d_in[10];
    const float* W1_at = (const float*)d_in[11];
    const float* b1_at = (const float*)d_in[12];
    const float* W1_ta = (const float*)d_in[13];
    const float* b1_ta = (const float*)d_in[14];
    const float* W2_aa = (const float*)d_in[15];
    const float* b2_aa = (const float*)d_in[16];
    const float* W2_at = (const float*)d_in[17];
    const float* b2_at = (const float*)d_in[18];
    const float* W2_ta = (const float*)d_in[19];
    const float* b2_ta = (const float*)d_in[20];
    const float* Wp_a  = (const float*)d_in[21];
    const float* bp_a  = (const float*)d_in[22];
    const float* Wp_t  = (const float*)d_in[23];
    const float* bp_t  = (const float*)d_in[24];

    int*   wi  = (int*)d_ws;
    float* wf  = (float*)d_ws;
    float* out = (float*)d_out;

    // zero the src-degree histograms
    hipMemsetAsync(wi + O_ATSRC, 0, 75000 * 4, stream);

    // pass 1: coarse bucket histogram (+ fused src degrees)
    p1_hist_kernel<<<NBLK1, 256, 0, stream>>>(dst_aa, dst_ta, dst_at, src_ta, src_at, wi);

    // scan + src coefs + U fuse in one dispatch
    aux_kernel<<<76, 1024, 0, stream>>>(wi, wf, W2_aa, W2_ta, W2_at, b2_aa, b2_ta, b2_at,
                                        Wp_a, bp_a, Wp_t, bp_t);

    // pass 1c: bucket scatter of packed records
    p1_scatter_kernel<<<NBLK1, 256, 0, stream>>>(src_aa, dst_aa, src_ta, dst_ta,
                                                 src_at, dst_at, wi + O_HIST, wi + O_REC);

    // pass 2: per-bucket -> ro + dst coefs + row-sorted records
    p2_kernel<<<NB, 256, 0, stream>>>(wi + O_HIST, wi + O_REC, wi + O_RO,
                                      wf + O_CAA, wf + O_CTAD, wf + O_CATD, wi + O_REC2);

    // conv1: edge-parallel LDS aggregation + dense matvec
    conv1_all_kernel<<<AGB + TGB, 256, 0, stream>>>(
        x_a, x_t, wi + O_RO, wi + O_REC2,
        wf + O_CAA, wf + O_CTAD, wf + O_CTAS, wf + O_CATS, wf + O_CATD,
        W1_aa, b1_aa, W1_ta, b1_ta, W1_at, b1_at, wf + O_U,
        wf + O_P, wf + O_Q, wf + O_R);

    // conv2 + projection: edge-parallel LDS accumulation
    out_all_kernel<<<AGB + TGB, 256, 0, stream>>>(
        wf + O_P, wf + O_Q, wf + O_R, wi + O_RO, wi + O_REC2,
        wf + O_CAA, wf + O_CTAD, wf + O_CATD, wf + O_U, out);
}

// Round 11
// 324.745 us; speedup vs baseline: 1.9548x; 1.9548x over previous
//
#include <hip/hip_runtime.h>

#define NA 50000
#define NT 25000
#define EAA 800000
#define EAT 400000
#define ETA 400000
#define NSEG 125000          // NA + NA + NT rows: [aa | ta | at]
#define TOTAL_E 1600000
#define NB 245               // coarse buckets of 512 rows
#define NBLK1 196            // pass-1 blocks
#define CHUNK 8192           // edges per pass-1 block

// ---- workspace layout (4-byte element offsets) ----
#define O_HIST    0          // int[48020]: hist[bucket][block] -> scanned bases
#define O_ATSRC   48064      // int[50000]
#define O_TASRC   98064      // int[25000]
#define O_RO      123072     // int[125001]: CSR row offsets
#define O_CAA     248128     // float[50000]: rsqrt(indeg_aa+1)
#define O_CTAD    298128     // float[50000]
#define O_CATD    348128     // float[25000]
#define O_CATS    373128     // float[50000]
#define O_CTAS    423128     // float[25000]
#define O_U       448128     // float[512]
#define O_P       448640     // float[100000]
#define O_Q       548640     // float[100000]
#define O_R       648640     // float[50000]
#define O_REC     698640     // int[1600000]: packed records (row_local<<16)|src
#define O_CSR     2298640    // ushort[1600000]: final CSR src indices (800000 ints)

__device__ __forceinline__ float bcast(float v, int l) {
    return __int_as_float(__builtin_amdgcn_readlane(__float_as_int(v), l));
}

// ---------- pass 1a: per-block coarse histogram (LDS) + fused src-degree atomics ----------
__global__ void __launch_bounds__(256)
p1_hist_kernel(const int* __restrict__ dst_aa, const int* __restrict__ dst_ta,
               const int* __restrict__ dst_at, const int* __restrict__ src_ta,
               const int* __restrict__ src_at, int* __restrict__ wi) {
    __shared__ int h[NB];
    for (int i = threadIdx.x; i < NB; i += 256) h[i] = 0;
    __syncthreads();
    int b = blockIdx.x;
    int t0 = b * CHUNK, t1 = min(t0 + CHUNK, TOTAL_E);
    for (int t = t0 + threadIdx.x; t < t1; t += 256) {
        int row;
        if (t < EAA) {
            row = dst_aa[t];
        } else if (t < EAA + ETA) {
            int u = t - EAA;
            row = NA + dst_ta[u];
            atomicAdd(&wi[O_TASRC + src_ta[u]], 1);
        } else {
            int u = t - EAA - ETA;
            row = 2 * NA + dst_at[u];
            atomicAdd(&wi[O_ATSRC + src_at[u]], 1);
        }
        atomicAdd(&h[row >> 9], 1);
    }
    __syncthreads();
    for (int i = threadIdx.x; i < NB; i += 256) wi[O_HIST + i * NBLK1 + b] = h[i];
}

// ---------- aux: block 0 = hist scan; blocks 1..74 = src coefs; block 75 = U fuse ----------
__global__ void __launch_bounds__(1024)
aux_kernel(int* __restrict__ wi, float* __restrict__ wf,
           const float* __restrict__ W2_aa, const float* __restrict__ W2_ta,
           const float* __restrict__ W2_at, const float* __restrict__ b2_aa,
           const float* __restrict__ b2_ta, const float* __restrict__ b2_at,
           const float* __restrict__ Wp_a, const float* __restrict__ bp_a,
           const float* __restrict__ Wp_t, const float* __restrict__ bp_t) {
    if (blockIdx.x == 0) {
        __shared__ int wsum[16];
        __shared__ int sCarry;
        int* h = wi + O_HIST;
        int tid = threadIdx.x, lane = tid & 63, wid = tid >> 6;
        if (tid == 0) sCarry = 0;
        __syncthreads();
        const int N2 = NB * NBLK1;
        for (int base = 0; base < N2; base += 1024) {
            int idx = base + tid;
            int v = (idx < N2) ? h[idx] : 0;
            int x = v;
#pragma unroll
            for (int off = 1; off < 64; off <<= 1) {
                int y = __shfl_up(x, off, 64);
                if (lane >= off) x += y;
            }
            if (lane == 63) wsum[wid] = x;
            __syncthreads();
            int wpre = 0, tot = 0;
            for (int w = 0; w < 16; ++w) {
                int s = wsum[w];
                if (w < wid) wpre += s;
                tot += s;
            }
            int excl = x - v + wpre + sCarry;
            if (idx < N2) h[idx] = excl;
            __syncthreads();
            if (tid == 0) sCarry += tot;
            __syncthreads();
        }
    } else if (blockIdx.x <= 74) {
        int t = (blockIdx.x - 1) * 1024 + threadIdx.x;
        if (t < 50000) {
            int d = wi[O_ATSRC + t];
            wf[O_CATS + t] = d > 0 ? rsqrtf((float)d) : 0.0f;
        } else if (t < 75000) {
            int i = t - 50000; int d = wi[O_TASRC + i];
            wf[O_CTAS + i] = d > 0 ? rsqrtf((float)d) : 0.0f;
        }
    } else {
        float* U = wf + O_U;
        int t = threadIdx.x;
        if (t < 128) {
            int k = t >> 1, j = t & 1;
            float a = 0.f;
            for (int f = 0; f < 64; ++f) a = fmaf(W2_aa[k * 64 + f], Wp_a[f * 2 + j], a);
            U[t] = a;
        } else if (t < 256) {
            int u = t - 128; int k = u >> 1, j = u & 1;
            float a = 0.f;
            for (int f = 0; f < 64; ++f) a = fmaf(W2_ta[k * 64 + f], Wp_a[f * 2 + j], a);
            U[128 + u] = a;
        } else if (t < 384) {
            int u = t - 256; int k = u >> 1, j = u & 1;
            float a = 0.f;
            for (int f = 0; f < 64; ++f) a = fmaf(W2_at[k * 64 + f], Wp_t[f * 2 + j], a);
            U[256 + u] = a;
        } else if (t < 386) {
            int j = t - 384;
            float a = bp_a[j];
            for (int f = 0; f < 64; ++f) a = fmaf(b2_aa[f] + b2_ta[f], Wp_a[f * 2 + j], a);
            U[384 + j] = a;
        } else if (t < 388) {
            int j = t - 386;
            float a = bp_t[j];
            for (int f = 0; f < 64; ++f) a = fmaf(b2_at[f], Wp_t[f * 2 + j], a);
            U[386 + j] = a;
        }
    }
}

// ---------- pass 1c: scatter packed records via LDS cursors (block-exclusive runs) ----------
__global__ void __launch_bounds__(256)
p1_scatter_kernel(const int* __restrict__ src_aa, const int* __restrict__ dst_aa,
                  const int* __restrict__ src_ta, const int* __restrict__ dst_ta,
                  const int* __restrict__ src_at, const int* __restrict__ dst_at,
                  const int* __restrict__ hist_g, int* __restrict__ rec) {
    __shared__ int cur[NB];
    int b = blockIdx.x;
    for (int i = threadIdx.x; i < NB; i += 256) cur[i] = hist_g[i * NBLK1 + b];
    __syncthreads();
    int t0 = b * CHUNK, t1 = min(t0 + CHUNK, TOTAL_E);
    for (int t = t0 + threadIdx.x; t < t1; t += 256) {
        int row, s;
        if (t < EAA) { row = dst_aa[t]; s = src_aa[t]; }
        else if (t < EAA + ETA) { int u = t - EAA; row = NA + dst_ta[u]; s = src_ta[u]; }
        else { int u = t - EAA - ETA; row = 2 * NA + dst_at[u]; s = src_at[u]; }
        int pos = atomicAdd(&cur[row >> 9], 1);
        rec[pos] = ((row & 511) << 16) | s;
    }
}

// ---------- pass 2: per-bucket degree count + LDS scan -> ro + dst coefs + CSR scatter ----------
__global__ void __launch_bounds__(256)
p2_kernel(const int* __restrict__ hist_g, const int* __restrict__ rec,
          int* __restrict__ ro, float* __restrict__ caa, float* __restrict__ ctad,
          float* __restrict__ catd, unsigned short* __restrict__ csr) {
    __shared__ int deg[512];
    __shared__ int rb[512];
    __shared__ int wsum[4];
    int k = blockIdx.x, tid = threadIdx.x, lane = tid & 63, wid = tid >> 6;
    int e0 = hist_g[k * NBLK1];
    int e1 = (k + 1 < NB) ? hist_g[(k + 1) * NBLK1] : TOTAL_E;
    deg[tid] = 0; deg[tid + 256] = 0;
    __syncthreads();
    for (int j = e0 + tid; j < e1; j += 256) atomicAdd(&deg[rec[j] >> 16], 1);
    __syncthreads();
    int d0 = deg[2 * tid], d1 = deg[2 * tid + 1];
    int v = d0 + d1;
    int x = v;
#pragma unroll
    for (int off = 1; off < 64; off <<= 1) {
        int y = __shfl_up(x, off, 64);
        if (lane >= off) x += y;
    }
    if (lane == 63) wsum[wid] = x;
    __syncthreads();
    int wpre = 0;
    for (int w = 0; w < wid; ++w) wpre += wsum[w];
    int pexcl = x - v + wpre;
    rb[2 * tid] = e0 + pexcl;
    rb[2 * tid + 1] = e0 + pexcl + d0;
    __syncthreads();
    for (int i = tid; i < 512; i += 256) {
        int g = k * 512 + i;
        if (g < NSEG) {
            ro[g] = rb[i];
            int d = deg[i];
            if (g < NA) caa[g] = rsqrtf((float)d + 1.0f);
            else if (g < 2 * NA) ctad[g - NA] = d > 0 ? rsqrtf((float)d) : 0.0f;
            else catd[g - 2 * NA] = d > 0 ? rsqrtf((float)d) : 0.0f;
        }
    }
    if (k == NB - 1 && tid == 0) ro[NSEG] = TOTAL_E;
    __syncthreads();
    for (int j = e0 + tid; j < e1; j += 256) {
        int rc = rec[j];
        int pos = atomicAdd(&rb[rc >> 16], 1);
        csr[pos] = (unsigned short)(rc & 0xFFFF);
    }
}

// ---------- conv1: gather + readlane-broadcast matvec (transposed b64 W in LDS) ----------
__global__ void __launch_bounds__(256)
conv1_all_kernel(const float* __restrict__ x_a, const float* __restrict__ x_t,
                 const int* __restrict__ ro, const unsigned short* __restrict__ csr,
                 const float* __restrict__ c_aa, const float* __restrict__ c_ta_d,
                 const float* __restrict__ c_ta_s, const float* __restrict__ c_at_s,
                 const float* __restrict__ c_at_d,
                 const float* __restrict__ W_aa, const float* __restrict__ b_aa,
                 const float* __restrict__ W_ta, const float* __restrict__ b_ta,
                 const float* __restrict__ W_at, const float* __restrict__ b_at,
                 const float* __restrict__ U,
                 float* __restrict__ p, float* __restrict__ q, float* __restrict__ r) {
    __shared__ float sW0[64 * 34];   // transposed: sW0[col*34 + k], pad 34 keeps b64 4-way
    __shared__ float sW1[64 * 34];
    int lane = threadIdx.x & 63;
    int wave = threadIdx.x >> 6;
    int e8 = lane >> 3, k4 = lane & 7;

    if (blockIdx.x < NA / 4) {
        // ---------- agents ----------
        for (int idx = threadIdx.x; idx < 2048; idx += 256) {
            int k = idx >> 6, col = idx & 63;
            sW0[col * 34 + k] = W_aa[idx];    // W_aa[k*64+col], coalesced
            sW1[col * 34 + k] = W_ta[idx];
        }
        __syncthreads();
        int i = blockIdx.x * 4 + wave;
        float ci = c_aa[i];
        float bias = b_aa[lane] + b_ta[lane];
        int b0 = ro[i], e0v = ro[i + 1];
        int b1 = ro[NA + i], e1v = ro[NA + i + 1];
        int na = e0v - b0, nt = e1v - b1;
        int sA = (lane < na) ? (int)csr[b0 + lane] : -1;
        int sT = (lane < nt) ? (int)csr[b1 + lane] : -1;

        float4 accA = make_float4(0.f, 0.f, 0.f, 0.f);
        int ngA = min(na, 64);
        for (int g = 0; g * 8 < ngA; ++g) {
            int s = __shfl(sA, g * 8 + e8, 64);
            if (s >= 0) {
                float w = c_aa[s];
                float4 xv = *(const float4*)(x_a + (size_t)s * 32 + k4 * 4);
                accA.x = fmaf(xv.x, w, accA.x);
                accA.y = fmaf(xv.y, w, accA.y);
                accA.z = fmaf(xv.z, w, accA.z);
                accA.w = fmaf(xv.w, w, accA.w);
            }
        }
        for (int j = b0 + 64 + e8; j < e0v; j += 8) {   // rare tail
            int s = csr[j];
            float w = c_aa[s];
            float4 xv = *(const float4*)(x_a + (size_t)s * 32 + k4 * 4);
            accA.x = fmaf(xv.x, w, accA.x);
            accA.y = fmaf(xv.y, w, accA.y);
            accA.z = fmaf(xv.z, w, accA.z);
            accA.w = fmaf(xv.w, w, accA.w);
        }
        if (e8 == 0) {  // self-loop
            float4 xv = *(const float4*)(x_a + (size_t)i * 32 + k4 * 4);
            accA.x = fmaf(xv.x, ci, accA.x);
            accA.y = fmaf(xv.y, ci, accA.y);
            accA.z = fmaf(xv.z, ci, accA.z);
            accA.w = fmaf(xv.w, ci, accA.w);
        }
        float4 accT = make_float4(0.f, 0.f, 0.f, 0.f);
        int ngT = min(nt, 64);
        for (int g = 0; g * 8 < ngT; ++g) {
            int s = __shfl(sT, g * 8 + e8, 64);
            if (s >= 0) {
                float w = c_ta_s[s];
                float4 xv = *(const float4*)(x_t + (size_t)s * 32 + k4 * 4);
                accT.x = fmaf(xv.x, w, accT.x);
                accT.y = fmaf(xv.y, w, accT.y);
                accT.z = fmaf(xv.z, w, accT.z);
                accT.w = fmaf(xv.w, w, accT.w);
            }
        }
        for (int j = b1 + 64 + e8; j < e1v; j += 8) {   // rare tail
            int s = csr[j];
            float w = c_ta_s[s];
            float4 xv = *(const float4*)(x_t + (size_t)s * 32 + k4 * 4);
            accT.x = fmaf(xv.x, w, accT.x);
            accT.y = fmaf(xv.y, w, accT.y);
            accT.z = fmaf(xv.z, w, accT.z);
            accT.w = fmaf(xv.w, w, accT.w);
        }
        // 3-level xor reduce over edge slots: every lane ends with its k4-slice sum
#pragma unroll
        for (int m = 8; m <= 32; m <<= 1) {
            accA.x += __shfl_xor(accA.x, m, 64);
            accA.y += __shfl_xor(accA.y, m, 64);
            accA.z += __shfl_xor(accA.z, m, 64);
            accA.w += __shfl_xor(accA.w, m, 64);
            accT.x += __shfl_xor(accT.x, m, 64);
            accT.y += __shfl_xor(accT.y, m, 64);
            accT.z += __shfl_xor(accT.z, m, 64);
            accT.w += __shfl_xor(accT.w, m, 64);
        }
        // matvec: broadcast slice g from lane g (readlane, no LDS), W via b64 LDS reads
        float hA = 0.f, hT = 0.f;
#pragma unroll
        for (int g = 0; g < 8; ++g) {
            float a0 = bcast(accA.x, g), a1 = bcast(accA.y, g);
            float a2 = bcast(accA.z, g), a3 = bcast(accA.w, g);
            float t0 = bcast(accT.x, g), t1 = bcast(accT.y, g);
            float t2 = bcast(accT.z, g), t3 = bcast(accT.w, g);
            float2 wa01 = *(const float2*)&sW0[lane * 34 + g * 4];
            float2 wa23 = *(const float2*)&sW0[lane * 34 + g * 4 + 2];
            float2 wt01 = *(const float2*)&sW1[lane * 34 + g * 4];
            float2 wt23 = *(const float2*)&sW1[lane * 34 + g * 4 + 2];
            hA = fmaf(a0, wa01.x, hA); hA = fmaf(a1, wa01.y, hA);
            hA = fmaf(a2, wa23.x, hA); hA = fmaf(a3, wa23.y, hA);
            hT = fmaf(t0, wt01.x, hT); hT = fmaf(t1, wt01.y, hT);
            hT = fmaf(t2, wt23.x, hT); hT = fmaf(t3, wt23.y, hT);
        }
        float h = fmaxf(bias + ci * hA + c_ta_d[i] * hT, 0.f);
        float p0 = h * U[lane * 2], p1 = h * U[lane * 2 + 1];
        float q0 = h * U[256 + lane * 2], q1 = h * U[256 + lane * 2 + 1];
#pragma unroll
        for (int m = 32; m; m >>= 1) {
            p0 += __shfl_xor(p0, m, 64);
            p1 += __shfl_xor(p1, m, 64);
            q0 += __shfl_xor(q0, m, 64);
            q1 += __shfl_xor(q1, m, 64);
        }
        if (lane == 0) {
            float cq = c_at_s[i];
            *(float2*)&p[i * 2] = make_float2(p0 * ci, p1 * ci);
            *(float2*)&q[i * 2] = make_float2(q0 * cq, q1 * cq);
        }
    } else {
        // ---------- targets ----------
        for (int idx = threadIdx.x; idx < 2048; idx += 256) {
            int k = idx >> 6, col = idx & 63;
            sW0[col * 34 + k] = W_at[idx];
        }
        __syncthreads();
        int i = (blockIdx.x - NA / 4) * 4 + wave;
        float bias = b_at[lane];
        int b0 = ro[2 * NA + i], e0v = ro[2 * NA + i + 1];
        int na = e0v - b0;
        int sA = (lane < na) ? (int)csr[b0 + lane] : -1;
        float4 acc = make_float4(0.f, 0.f, 0.f, 0.f);
        int ng = min(na, 64);
        for (int g = 0; g * 8 < ng; ++g) {
            int s = __shfl(sA, g * 8 + e8, 64);
            if (s >= 0) {
                float w = c_at_s[s];
                float4 xv = *(const float4*)(x_a + (size_t)s * 32 + k4 * 4);
                acc.x = fmaf(xv.x, w, acc.x);
                acc.y = fmaf(xv.y, w, acc.y);
                acc.z = fmaf(xv.z, w, acc.z);
                acc.w = fmaf(xv.w, w, acc.w);
            }
        }
        for (int j = b0 + 64 + e8; j < e0v; j += 8) {   // rare tail
            int s = csr[j];
            float w = c_at_s[s];
            float4 xv = *(const float4*)(x_a + (size_t)s * 32 + k4 * 4);
            acc.x = fmaf(xv.x, w, acc.x);
            acc.y = fmaf(xv.y, w, acc.y);
            acc.z = fmaf(xv.z, w, acc.z);
            acc.w = fmaf(xv.w, w, acc.w);
        }
#pragma unroll
        for (int m = 8; m <= 32; m <<= 1) {
            acc.x += __shfl_xor(acc.x, m, 64);
            acc.y += __shfl_xor(acc.y, m, 64);
            acc.z += __shfl_xor(acc.z, m, 64);
            acc.w += __shfl_xor(acc.w, m, 64);
        }
        float hA = 0.f;
#pragma unroll
        for (int g = 0; g < 8; ++g) {
            float a0 = bcast(acc.x, g), a1 = bcast(acc.y, g);
            float a2 = bcast(acc.z, g), a3 = bcast(acc.w, g);
            float2 w01 = *(const float2*)&sW0[lane * 34 + g * 4];
            float2 w23 = *(const float2*)&sW0[lane * 34 + g * 4 + 2];
            hA = fmaf(a0, w01.x, hA); hA = fmaf(a1, w01.y, hA);
            hA = fmaf(a2, w23.x, hA); hA = fmaf(a3, w23.y, hA);
        }
        float h = fmaxf(bias + c_at_d[i] * hA, 0.f);
        float r0 = h * U[128 + lane * 2], r1 = h * U[128 + lane * 2 + 1];
#pragma unroll
        for (int m = 32; m; m >>= 1) {
            r0 += __shfl_xor(r0, m, 64);
            r1 += __shfl_xor(r1, m, 64);
        }
        if (lane == 0) {
            float cr = c_ta_s[i];
            *(float2*)&r[i * 2] = make_float2(r0 * cr, r1 * cr);
        }
    }
}

// ---------- conv2+proj: one wave per node, 32 edge slots x 2 comps ----------
__global__ void __launch_bounds__(256)
out_all_kernel(const float* __restrict__ p, const float* __restrict__ q,
               const float* __restrict__ r, const int* __restrict__ ro,
               const unsigned short* __restrict__ csr,
               const float* __restrict__ c_aa, const float* __restrict__ c_ta_d,
               const float* __restrict__ c_at_d, const float* __restrict__ U,
               float* __restrict__ out) {
    int wgid = blockIdx.x * 4 + (threadIdx.x >> 6);
    int lane = threadIdx.x & 63;
    int slot = lane >> 1, j = lane & 1;
    if (wgid < NA) {
        int i = wgid;
        int b0 = ro[i], n0 = ro[i + 1] - b0;
        float accA = (slot == 0) ? p[i * 2 + j] : 0.f;   // self-loop (p premultiplied)
        for (int e = slot; e < n0; e += 32) accA += p[(int)csr[b0 + e] * 2 + j];
        int b1 = ro[NA + i], n1 = ro[NA + i + 1] - b1;
        float accT = 0.f;
        for (int e = slot; e < n1; e += 32) accT += r[(int)csr[b1 + e] * 2 + j];
#pragma unroll
        for (int m = 2; m <= 32; m <<= 1) {
            accA += __shfl_xor(accA, m, 64);
            accT += __shfl_xor(accT, m, 64);
        }
        if (lane < 2) out[i * 2 + j] = U[384 + j] + accA * c_aa[i] + accT * c_ta_d[i];
    } else {
        int i = wgid - NA;
        int b0 = ro[2 * NA + i], n0 = ro[2 * NA + i + 1] - b0;
        float acc = 0.f;
        for (int e = slot; e < n0; e += 32) acc += q[(int)csr[b0 + e] * 2 + j];
#pragma unroll
        for (int m = 2; m <= 32; m <<= 1) acc += __shfl_xor(acc, m, 64);
        if (lane < 2) out[NA * 2 + i * 2 + j] = U[386 + j] + acc * c_at_d[i];
    }
}

extern "C" void kernel_launch(void* const* d_in, const int* in_sizes, int n_in,
                              void* d_out, int out_size, void* d_ws, size_t ws_size,
                              hipStream_t stream) {
    const float* x_a   = (const float*)d_in[1];
    const float* x_t   = (const float*)d_in[2];
    const int* src_aa  = (const int*)d_in[3];
    const int* dst_aa  = (const int*)d_in[4];
    const int* src_at  = (const int*)d_in[5];
    const int* dst_at  = (const int*)d_in[6];
    const int* src_ta  = (const int*)d_in[7];
    const int* dst_ta  = (const int*)d_in[8];
    const float* W1_aa = (const float*)d_in[9];
    const float* b1_aa = (const float*)d_in[10];
    const float* W1_at = (const float*)d_in[11];
    const float* b1_at = (const float*)d_in[12];
    const float* W1_ta = (const float*)d_in[13];
    const float* b1_ta = (const float*)d_in[14];
    const float* W2_aa = (const float*)d_in[15];
    const float* b2_aa = (const float*)d_in[16];
    const float* W2_at = (const float*)d_in[17];
    const float* b2_at = (const float*)d_in[18];
    const float* W2_ta = (const float*)d_in[19];
    const float* b2_ta = (const float*)d_in[20];
    const float* Wp_a  = (const float*)d_in[21];
    const float* bp_a  = (const float*)d_in[22];
    const float* Wp_t  = (const float*)d_in[23];
    const float* bp_t  = (const float*)d_in[24];

    int*   wi  = (int*)d_ws;
    float* wf  = (float*)d_ws;
    unsigned short* csr = (unsigned short*)(wi + O_CSR);
    float* out = (float*)d_out;

    // zero the src-degree histograms
    hipMemsetAsync(wi + O_ATSRC, 0, 75000 * 4, stream);

    // pass 1: coarse bucket histogram (+ fused src degrees)
    p1_hist_kernel<<<NBLK1, 256, 0, stream>>>(dst_aa, dst_ta, dst_at, src_ta, src_at, wi);

    // scan + src coefs + U fuse in one dispatch
    aux_kernel<<<76, 1024, 0, stream>>>(wi, wf, W2_aa, W2_ta, W2_at, b2_aa, b2_ta, b2_at,
                                        Wp_a, bp_a, Wp_t, bp_t);

    // pass 1c: bucket scatter of packed records
    p1_scatter_kernel<<<NBLK1, 256, 0, stream>>>(src_aa, dst_aa, src_ta, dst_ta,
                                                 src_at, dst_at, wi + O_HIST, wi + O_REC);

    // pass 2: per-bucket -> ro + dst coefs + final CSR
    p2_kernel<<<NB, 256, 0, stream>>>(wi + O_HIST, wi + O_REC, wi + O_RO,
                                      wf + O_CAA, wf + O_CTAD, wf + O_CATD, csr);

    // conv1: gather + readlane matvec
    conv1_all_kernel<<<NA / 4 + NT / 4, 256, 0, stream>>>(
        x_a, x_t, wi + O_RO, csr,
        wf + O_CAA, wf + O_CTAD, wf + O_CTAS, wf + O_CATS, wf + O_CATD,
        W1_aa, b1_aa, W1_ta, b1_ta, W1_at, b1_at, wf + O_U,
        wf + O_P, wf + O_Q, wf + O_R);

    // conv2 + projection, wave per node
    out_all_kernel<<<(NA + NT) / 4, 256, 0, stream>>>(
        wf + O_P, wf + O_Q, wf + O_R, wi + O_RO, csr,
        wf + O_CAA, wf + O_CTAD, wf + O_CATD, wf + O_U, out);
}

// Round 12
// 291.022 us; speedup vs baseline: 2.1813x; 1.1159x over previous
//
#include <hip/hip_runtime.h>

#define NA 50000
#define NT 25000
#define EAA 800000
#define EAT 400000
#define ETA 400000
#define NSEG 125000          // NA + NA + NT rows: [aa | ta | at]
#define TOTAL_E 1600000
#define NB 245               // coarse buckets of 512 rows
#define NBLK1 196            // pass-1 blocks
#define CHUNK 8192           // edges per pass-1 block

// ---- workspace layout (4-byte element offsets) ----
#define O_HIST    0          // int[48020]: per-(bucket,block) within-bucket offsets
#define O_ATSRC   48064      // int[50000]
#define O_TASRC   98064      // int[25000]
#define O_RO      123072     // int[125001]: CSR row offsets
#define O_CAA     248128     // float[50000]: rsqrt(indeg_aa+1)
#define O_CTAD    298128     // float[50000]
#define O_CATD    348128     // float[25000]
#define O_CATS    373128     // float[50000]
#define O_CTAS    423128     // float[25000]
#define O_U       448128     // float[512]
#define O_P       448640     // float[100000]
#define O_Q       548640     // float[100000]
#define O_R       648640     // float[50000]
#define O_REC     698640     // int[1600000]: packed records (row_local<<16)|src
#define O_CSR     2298640    // ushort[1600000]: final CSR src indices (800000 ints)
#define O_BTOT    3098640    // int[256]: per-bucket totals (atomic)
#define O_BBASE   3098896    // int[256]: scanned bucket bases

__device__ __forceinline__ float bcast(float v, int l) {
    return __int_as_float(__builtin_amdgcn_readlane(__float_as_int(v), l));
}

// ---------- pass 1a: per-block coarse histogram + atomic bucket reservation ----------
__global__ void __launch_bounds__(256)
p1_hist_kernel(const int* __restrict__ dst_aa, const int* __restrict__ dst_ta,
               const int* __restrict__ dst_at, const int* __restrict__ src_ta,
               const int* __restrict__ src_at, int* __restrict__ wi) {
    __shared__ int h[NB];
    for (int i = threadIdx.x; i < NB; i += 256) h[i] = 0;
    __syncthreads();
    int b = blockIdx.x;
    int t0 = b * CHUNK, t1 = min(t0 + CHUNK, TOTAL_E);
    for (int t = t0 + threadIdx.x; t < t1; t += 256) {
        int row;
        if (t < EAA) {
            row = dst_aa[t];
        } else if (t < EAA + ETA) {
            int u = t - EAA;
            row = NA + dst_ta[u];
            atomicAdd(&wi[O_TASRC + src_ta[u]], 1);
        } else {
            int u = t - EAA - ETA;
            row = 2 * NA + dst_at[u];
            atomicAdd(&wi[O_ATSRC + src_at[u]], 1);
        }
        atomicAdd(&h[row >> 9], 1);
    }
    __syncthreads();
    // reserve this block's slice of each bucket
    for (int i = threadIdx.x; i < NB; i += 256) {
        int base = atomicAdd(&wi[O_BTOT + i], h[i]);
        wi[O_HIST + i * NBLK1 + b] = base;
    }
}

// ---------- aux: block 0 = tiny 245 bucket scan; blocks 1..74 = src coefs; block 75 = U fuse ----------
__global__ void __launch_bounds__(1024)
aux_kernel(int* __restrict__ wi, float* __restrict__ wf,
           const float* __restrict__ W2_aa, const float* __restrict__ W2_ta,
           const float* __restrict__ W2_at, const float* __restrict__ b2_aa,
           const float* __restrict__ b2_ta, const float* __restrict__ b2_at,
           const float* __restrict__ Wp_a, const float* __restrict__ bp_a,
           const float* __restrict__ Wp_t, const float* __restrict__ bp_t) {
    if (blockIdx.x == 0) {
        __shared__ int s[NB];
        int t = threadIdx.x;
        if (t < NB) s[t] = wi[O_BTOT + t];
        __syncthreads();
        // Hillis-Steele inclusive scan over 245 (first 256 threads)
        for (int off = 1; off < NB; off <<= 1) {
            int x = 0;
            if (t < NB && t >= off) x = s[t - off];
            __syncthreads();
            if (t < NB) s[t] += x;
            __syncthreads();
        }
        if (t < NB) wi[O_BBASE + t] = s[t] - wi[O_BTOT + t];   // exclusive
        if (t == 0) wi[O_BBASE + NB] = TOTAL_E;
    } else if (blockIdx.x <= 74) {
        int t = (blockIdx.x - 1) * 1024 + threadIdx.x;
        if (t < 50000) {
            int d = wi[O_ATSRC + t];
            wf[O_CATS + t] = d > 0 ? rsqrtf((float)d) : 0.0f;
        } else if (t < 75000) {
            int i = t - 50000; int d = wi[O_TASRC + i];
            wf[O_CTAS + i] = d > 0 ? rsqrtf((float)d) : 0.0f;
        }
    } else {
        float* U = wf + O_U;
        int t = threadIdx.x;
        if (t < 128) {
            int k = t >> 1, j = t & 1;
            float a = 0.f;
            for (int f = 0; f < 64; ++f) a = fmaf(W2_aa[k * 64 + f], Wp_a[f * 2 + j], a);
            U[t] = a;
        } else if (t < 256) {
            int u = t - 128; int k = u >> 1, j = u & 1;
            float a = 0.f;
            for (int f = 0; f < 64; ++f) a = fmaf(W2_ta[k * 64 + f], Wp_a[f * 2 + j], a);
            U[128 + u] = a;
        } else if (t < 384) {
            int u = t - 256; int k = u >> 1, j = u & 1;
            float a = 0.f;
            for (int f = 0; f < 64; ++f) a = fmaf(W2_at[k * 64 + f], Wp_t[f * 2 + j], a);
            U[256 + u] = a;
        } else if (t < 386) {
            int j = t - 384;
            float a = bp_a[j];
            for (int f = 0; f < 64; ++f) a = fmaf(b2_aa[f] + b2_ta[f], Wp_a[f * 2 + j], a);
            U[384 + j] = a;
        } else if (t < 388) {
            int j = t - 386;
            float a = bp_t[j];
            for (int f = 0; f < 64; ++f) a = fmaf(b2_at[f], Wp_t[f * 2 + j], a);
            U[386 + j] = a;
        }
    }
}

// ---------- pass 1c: scatter packed records via LDS cursors (atomic-reserved runs) ----------
__global__ void __launch_bounds__(256)
p1_scatter_kernel(const int* __restrict__ src_aa, const int* __restrict__ dst_aa,
                  const int* __restrict__ src_ta, const int* __restrict__ dst_ta,
                  const int* __restrict__ src_at, const int* __restrict__ dst_at,
                  const int* __restrict__ wi, int* __restrict__ rec) {
    __shared__ int cur[NB];
    int b = blockIdx.x;
    for (int i = threadIdx.x; i < NB; i += 256)
        cur[i] = wi[O_BBASE + i] + wi[O_HIST + i * NBLK1 + b];
    __syncthreads();
    int t0 = b * CHUNK, t1 = min(t0 + CHUNK, TOTAL_E);
    for (int t = t0 + threadIdx.x; t < t1; t += 256) {
        int row, s;
        if (t < EAA) { row = dst_aa[t]; s = src_aa[t]; }
        else if (t < EAA + ETA) { int u = t - EAA; row = NA + dst_ta[u]; s = src_ta[u]; }
        else { int u = t - EAA - ETA; row = 2 * NA + dst_at[u]; s = src_at[u]; }
        int pos = atomicAdd(&cur[row >> 9], 1);
        rec[pos] = ((row & 511) << 16) | s;
    }
}

// ---------- pass 2: per-bucket degree count + LDS scan -> ro + dst coefs + CSR scatter ----------
__global__ void __launch_bounds__(256)
p2_kernel(const int* __restrict__ wi, const int* __restrict__ rec,
          int* __restrict__ ro, float* __restrict__ caa, float* __restrict__ ctad,
          float* __restrict__ catd, unsigned short* __restrict__ csr) {
    __shared__ int deg[512];
    __shared__ int rb[512];
    __shared__ int wsum[4];
    int k = blockIdx.x, tid = threadIdx.x, lane = tid & 63, wid = tid >> 6;
    int e0 = wi[O_BBASE + k];
    int e1 = wi[O_BBASE + k + 1];
    deg[tid] = 0; deg[tid + 256] = 0;
    __syncthreads();
    for (int j = e0 + tid; j < e1; j += 256) atomicAdd(&deg[rec[j] >> 16], 1);
    __syncthreads();
    int d0 = deg[2 * tid], d1 = deg[2 * tid + 1];
    int v = d0 + d1;
    int x = v;
#pragma unroll
    for (int off = 1; off < 64; off <<= 1) {
        int y = __shfl_up(x, off, 64);
        if (lane >= off) x += y;
    }
    if (lane == 63) wsum[wid] = x;
    __syncthreads();
    int wpre = 0;
    for (int w = 0; w < wid; ++w) wpre += wsum[w];
    int pexcl = x - v + wpre;
    rb[2 * tid] = e0 + pexcl;
    rb[2 * tid + 1] = e0 + pexcl + d0;
    __syncthreads();
    for (int i = tid; i < 512; i += 256) {
        int g = k * 512 + i;
        if (g < NSEG) {
            ro[g] = rb[i];
            int d = deg[i];
            if (g < NA) caa[g] = rsqrtf((float)d + 1.0f);
            else if (g < 2 * NA) ctad[g - NA] = d > 0 ? rsqrtf((float)d) : 0.0f;
            else catd[g - 2 * NA] = d > 0 ? rsqrtf((float)d) : 0.0f;
        }
    }
    if (k == NB - 1 && tid == 0) ro[NSEG] = TOTAL_E;
    __syncthreads();
    for (int j = e0 + tid; j < e1; j += 256) {
        int rc = rec[j];
        int pos = atomicAdd(&rb[rc >> 16], 1);
        csr[pos] = (unsigned short)(rc & 0xFFFF);
    }
}

// ---------- conv1: direct-load gather + readlane-broadcast matvec (transposed b64 W in LDS) ----------
__global__ void __launch_bounds__(256)
conv1_all_kernel(const float* __restrict__ x_a, const float* __restrict__ x_t,
                 const int* __restrict__ ro, const unsigned short* __restrict__ csr,
                 const float* __restrict__ c_aa, const float* __restrict__ c_ta_d,
                 const float* __restrict__ c_ta_s, const float* __restrict__ c_at_s,
                 const float* __restrict__ c_at_d,
                 const float* __restrict__ W_aa, const float* __restrict__ b_aa,
                 const float* __restrict__ W_ta, const float* __restrict__ b_ta,
                 const float* __restrict__ W_at, const float* __restrict__ b_at,
                 const float* __restrict__ U,
                 float* __restrict__ p, float* __restrict__ q, float* __restrict__ r) {
    __shared__ float sW0[64 * 34];   // transposed: sW0[col*34 + k]
    __shared__ float sW1[64 * 34];
    int lane = threadIdx.x & 63;
    int wave = threadIdx.x >> 6;
    int e8 = lane >> 3, k4 = lane & 7;

    if (blockIdx.x < NA / 4) {
        // ---------- agents ----------
        for (int idx = threadIdx.x; idx < 2048; idx += 256) {
            int k = idx >> 6, col = idx & 63;
            sW0[col * 34 + k] = W_aa[idx];
            sW1[col * 34 + k] = W_ta[idx];
        }
        __syncthreads();
        int i = blockIdx.x * 4 + wave;
        float ci = c_aa[i];
        float bias = b_aa[lane] + b_ta[lane];
        int b0 = ro[i], e0v = ro[i + 1];
        int b1 = ro[NA + i], e1v = ro[NA + i + 1];

        float4 accA = make_float4(0.f, 0.f, 0.f, 0.f);
        for (int j = b0 + e8; j < e0v; j += 8) {
            int s = csr[j];
            float w = c_aa[s];
            float4 xv = *(const float4*)(x_a + (size_t)s * 32 + k4 * 4);
            accA.x = fmaf(xv.x, w, accA.x);
            accA.y = fmaf(xv.y, w, accA.y);
            accA.z = fmaf(xv.z, w, accA.z);
            accA.w = fmaf(xv.w, w, accA.w);
        }
        if (e8 == 0) {  // self-loop
            float4 xv = *(const float4*)(x_a + (size_t)i * 32 + k4 * 4);
            accA.x = fmaf(xv.x, ci, accA.x);
            accA.y = fmaf(xv.y, ci, accA.y);
            accA.z = fmaf(xv.z, ci, accA.z);
            accA.w = fmaf(xv.w, ci, accA.w);
        }
        float4 accT = make_float4(0.f, 0.f, 0.f, 0.f);
        for (int j = b1 + e8; j < e1v; j += 8) {
            int s = csr[j];
            float w = c_ta_s[s];
            float4 xv = *(const float4*)(x_t + (size_t)s * 32 + k4 * 4);
            accT.x = fmaf(xv.x, w, accT.x);
            accT.y = fmaf(xv.y, w, accT.y);
            accT.z = fmaf(xv.z, w, accT.z);
            accT.w = fmaf(xv.w, w, accT.w);
        }
#pragma unroll
        for (int m = 8; m <= 32; m <<= 1) {
            accA.x += __shfl_xor(accA.x, m, 64);
            accA.y += __shfl_xor(accA.y, m, 64);
            accA.z += __shfl_xor(accA.z, m, 64);
            accA.w += __shfl_xor(accA.w, m, 64);
            accT.x += __shfl_xor(accT.x, m, 64);
            accT.y += __shfl_xor(accT.y, m, 64);
            accT.z += __shfl_xor(accT.z, m, 64);
            accT.w += __shfl_xor(accT.w, m, 64);
        }
        float hA = 0.f, hT = 0.f;
#pragma unroll
        for (int g = 0; g < 8; ++g) {
            float a0 = bcast(accA.x, g), a1 = bcast(accA.y, g);
            float a2 = bcast(accA.z, g), a3 = bcast(accA.w, g);
            float t0 = bcast(accT.x, g), t1 = bcast(accT.y, g);
            float t2 = bcast(accT.z, g), t3 = bcast(accT.w, g);
            float2 wa01 = *(const float2*)&sW0[lane * 34 + g * 4];
            float2 wa23 = *(const float2*)&sW0[lane * 34 + g * 4 + 2];
            float2 wt01 = *(const float2*)&sW1[lane * 34 + g * 4];
            float2 wt23 = *(const float2*)&sW1[lane * 34 + g * 4 + 2];
            hA = fmaf(a0, wa01.x, hA); hA = fmaf(a1, wa01.y, hA);
            hA = fmaf(a2, wa23.x, hA); hA = fmaf(a3, wa23.y, hA);
            hT = fmaf(t0, wt01.x, hT); hT = fmaf(t1, wt01.y, hT);
            hT = fmaf(t2, wt23.x, hT); hT = fmaf(t3, wt23.y, hT);
        }
        float h = fmaxf(bias + ci * hA + c_ta_d[i] * hT, 0.f);
        float p0 = h * U[lane * 2], p1 = h * U[lane * 2 + 1];
        float q0 = h * U[256 + lane * 2], q1 = h * U[256 + lane * 2 + 1];
#pragma unroll
        for (int m = 32; m; m >>= 1) {
            p0 += __shfl_xor(p0, m, 64);
            p1 += __shfl_xor(p1, m, 64);
            q0 += __shfl_xor(q0, m, 64);
            q1 += __shfl_xor(q1, m, 64);
        }
        if (lane == 0) {
            float cq = c_at_s[i];
            *(float2*)&p[i * 2] = make_float2(p0 * ci, p1 * ci);
            *(float2*)&q[i * 2] = make_float2(q0 * cq, q1 * cq);
        }
    } else {
        // ---------- targets ----------
        for (int idx = threadIdx.x; idx < 2048; idx += 256) {
            int k = idx >> 6, col = idx & 63;
            sW0[col * 34 + k] = W_at[idx];
        }
        __syncthreads();
        int i = (blockIdx.x - NA / 4) * 4 + wave;
        float bias = b_at[lane];
        int b0 = ro[2 * NA + i], e0v = ro[2 * NA + i + 1];
        float4 acc = make_float4(0.f, 0.f, 0.f, 0.f);
        for (int j = b0 + e8; j < e0v; j += 8) {
            int s = csr[j];
            float w = c_at_s[s];
            float4 xv = *(const float4*)(x_a + (size_t)s * 32 + k4 * 4);
            acc.x = fmaf(xv.x, w, acc.x);
            acc.y = fmaf(xv.y, w, acc.y);
            acc.z = fmaf(xv.z, w, acc.z);
            acc.w = fmaf(xv.w, w, acc.w);
        }
#pragma unroll
        for (int m = 8; m <= 32; m <<= 1) {
            acc.x += __shfl_xor(acc.x, m, 64);
            acc.y += __shfl_xor(acc.y, m, 64);
            acc.z += __shfl_xor(acc.z, m, 64);
            acc.w += __shfl_xor(acc.w, m, 64);
        }
        float hA = 0.f;
#pragma unroll
        for (int g = 0; g < 8; ++g) {
            float a0 = bcast(acc.x, g), a1 = bcast(acc.y, g);
            float a2 = bcast(acc.z, g), a3 = bcast(acc.w, g);
            float2 w01 = *(const float2*)&sW0[lane * 34 + g * 4];
            float2 w23 = *(const float2*)&sW0[lane * 34 + g * 4 + 2];
            hA = fmaf(a0, w01.x, hA); hA = fmaf(a1, w01.y, hA);
            hA = fmaf(a2, w23.x, hA); hA = fmaf(a3, w23.y, hA);
        }
        float h = fmaxf(bias + c_at_d[i] * hA, 0.f);
        float r0 = h * U[128 + lane * 2], r1 = h * U[128 + lane * 2 + 1];
#pragma unroll
        for (int m = 32; m; m >>= 1) {
            r0 += __shfl_xor(r0, m, 64);
            r1 += __shfl_xor(r1, m, 64);
        }
        if (lane == 0) {
            float cr = c_ta_s[i];
            *(float2*)&r[i * 2] = make_float2(r0 * cr, r1 * cr);
        }
    }
}

// ---------- conv2+proj: one wave per node, 32 edge slots x 2 comps ----------
__global__ void __launch_bounds__(256)
out_all_kernel(const float* __restrict__ p, const float* __restrict__ q,
               const float* __restrict__ r, const int* __restrict__ ro,
               const unsigned short* __restrict__ csr,
               const float* __restrict__ c_aa, const float* __restrict__ c_ta_d,
               const float* __restrict__ c_at_d, const float* __restrict__ U,
               float* __restrict__ out) {
    int wgid = blockIdx.x * 4 + (threadIdx.x >> 6);
    int lane = threadIdx.x & 63;
    int slot = lane >> 1, j = lane & 1;
    if (wgid < NA) {
        int i = wgid;
        int b0 = ro[i], n0 = ro[i + 1] - b0;
        float accA = (slot == 0) ? p[i * 2 + j] : 0.f;   // self-loop (p premultiplied)
        for (int e = slot; e < n0; e += 32) accA += p[(int)csr[b0 + e] * 2 + j];
        int b1 = ro[NA + i], n1 = ro[NA + i + 1] - b1;
        float accT = 0.f;
        for (int e = slot; e < n1; e += 32) accT += r[(int)csr[b1 + e] * 2 + j];
#pragma unroll
        for (int m = 2; m <= 32; m <<= 1) {
            accA += __shfl_xor(accA, m, 64);
            accT += __shfl_xor(accT, m, 64);
        }
        if (lane < 2) out[i * 2 + j] = U[384 + j] + accA * c_aa[i] + accT * c_ta_d[i];
    } else {
        int i = wgid - NA;
        int b0 = ro[2 * NA + i], n0 = ro[2 * NA + i + 1] - b0;
        float acc = 0.f;
        for (int e = slot; e < n0; e += 32) acc += q[(int)csr[b0 + e] * 2 + j];
#pragma unroll
        for (int m = 2; m <= 32; m <<= 1) acc += __shfl_xor(acc, m, 64);
        if (lane < 2) out[NA * 2 + i * 2 + j] = U[386 + j] + acc * c_at_d[i];
    }
}

extern "C" void kernel_launch(void* const* d_in, const int* in_sizes, int n_in,
                              void* d_out, int out_size, void* d_ws, size_t ws_size,
                              hipStream_t stream) {
    const float* x_a   = (const float*)d_in[1];
    const float* x_t   = (const float*)d_in[2];
    const int* src_aa  = (const int*)d_in[3];
    const int* dst_aa  = (const int*)d_in[4];
    const int* src_at  = (const int*)d_in[5];
    const int* dst_at  = (const int*)d_in[6];
    const int* src_ta  = (const int*)d_in[7];
    const int* dst_ta  = (const int*)d_in[8];
    const float* W1_aa = (const float*)d_in[9];
    const float* b1_aa = (const float*)d_in[10];
    const float* W1_at = (const float*)d_in[11];
    const float* b1_at = (const float*)d_in[12];
    const float* W1_ta = (const float*)d_in[13];
    const float* b1_ta = (const float*)d_in[14];
    const float* W2_aa = (const float*)d_in[15];
    const float* b2_aa = (const float*)d_in[16];
    const float* W2_at = (const float*)d_in[17];
    const float* b2_at = (const float*)d_in[18];
    const float* W2_ta = (const float*)d_in[19];
    const float* b2_ta = (const float*)d_in[20];
    const float* Wp_a  = (const float*)d_in[21];
    const float* bp_a  = (const float*)d_in[22];
    const float* Wp_t  = (const float*)d_in[23];
    const float* bp_t  = (const float*)d_in[24];

    int*   wi  = (int*)d_ws;
    float* wf  = (float*)d_ws;
    unsigned short* csr = (unsigned short*)(wi + O_CSR);
    float* out = (float*)d_out;

    // zero the src-degree histograms + bucket totals
    hipMemsetAsync(wi + O_ATSRC, 0, 75000 * 4, stream);
    hipMemsetAsync(wi + O_BTOT, 0, 256 * 4, stream);

    // pass 1: coarse bucket histogram + atomic reservation (+ fused src degrees)
    p1_hist_kernel<<<NBLK1, 256, 0, stream>>>(dst_aa, dst_ta, dst_at, src_ta, src_at, wi);

    // tiny bucket scan + src coefs + U fuse in one dispatch
    aux_kernel<<<76, 1024, 0, stream>>>(wi, wf, W2_aa, W2_ta, W2_at, b2_aa, b2_ta, b2_at,
                                        Wp_a, bp_a, Wp_t, bp_t);

    // pass 1c: bucket scatter of packed records
    p1_scatter_kernel<<<NBLK1, 256, 0, stream>>>(src_aa, dst_aa, src_ta, dst_ta,
                                                 src_at, dst_at, wi, wi + O_REC);

    // pass 2: per-bucket -> ro + dst coefs + final CSR
    p2_kernel<<<NB, 256, 0, stream>>>(wi, wi + O_REC, wi + O_RO,
                                      wf + O_CAA, wf + O_CTAD, wf + O_CATD, csr);

    // conv1: direct-load gather + readlane matvec
    conv1_all_kernel<<<NA / 4 + NT / 4, 256, 0, stream>>>(
        x_a, x_t, wi + O_RO, csr,
        wf + O_CAA, wf + O_CTAD, wf + O_CTAS, wf + O_CATS, wf + O_CATD,
        W1_aa, b1_aa, W1_ta, b1_ta, W1_at, b1_at, wf + O_U,
        wf + O_P, wf + O_Q, wf + O_R);

    // conv2 + projection, wave per node
    out_all_kernel<<<(NA + NT) / 4, 256, 0, stream>>>(
        wf + O_P, wf + O_Q, wf + O_R, wi + O_RO, csr,
        wf + O_CAA, wf + O_CTAD, wf + O_CATD, wf + O_U, out);
}

// Round 13
// 286.216 us; speedup vs baseline: 2.2179x; 1.0168x over previous
//
#include <hip/hip_runtime.h>

#define NA 50000
#define NT 25000
#define EAA 800000
#define EAT 400000
#define ETA 400000
#define NSEG 125000          // NA + NA + NT rows: [aa | ta | at]
#define TOTAL_E 1600000
#define NB 245               // coarse buckets of 512 rows
#define NBLK1 196            // pass-1 blocks
#define CHUNK 8192           // edges per pass-1 block
#define SRCH_STRIDE 75008    // per-copy src-histogram stride: at[50000] | ta[25000] | pad

// ---- workspace layout (4-byte element offsets) ----
#define O_HIST    0          // int[48020]: per-(bucket,block) within-bucket offsets
#define O_SRCH    48064      // int[8*75008]: 8 XCD-local src-degree histogram copies
#define O_RO      648128     // int[125001]: CSR row offsets
#define O_CAA     773136     // float[50000]: rsqrt(indeg_aa+1)
#define O_CTAD    823136     // float[50000]
#define O_CATD    873136     // float[25000]
#define O_CATS    898136     // float[50000]
#define O_CTAS    948136     // float[25000]
#define O_U       973648     // float[512]  (948136+25000=973136; pad to 973648)
#define O_P       974160     // float[100000]
#define O_Q       1074160    // float[100000]
#define O_R       1174160    // float[50000]
#define O_REC     1224160    // int[1600000]: packed records (row_local<<16)|src
#define O_CSR     2824160    // ushort[1600000] = 800000 ints
#define O_BTOT    3624160    // int[256]: per-bucket totals (atomic)
#define O_BBASE   3624416    // int[256]: scanned bucket bases

__device__ __forceinline__ float bcast(float v, int l) {
    return __int_as_float(__builtin_amdgcn_readlane(__float_as_int(v), l));
}

// ---------- pass 1a: coarse histogram + atomic bucket reservation + XCD-local src degrees ----------
__global__ void __launch_bounds__(256)
p1_hist_kernel(const int* __restrict__ dst_aa, const int* __restrict__ dst_ta,
               const int* __restrict__ dst_at, const int* __restrict__ src_ta,
               const int* __restrict__ src_at, int* __restrict__ wi) {
    __shared__ int h[NB];
    for (int i = threadIdx.x; i < NB; i += 256) h[i] = 0;
    __syncthreads();
    int b = blockIdx.x;
    int* srch = wi + O_SRCH + (b & 7) * SRCH_STRIDE;   // XCD-local copy
    int t0 = b * CHUNK, t1 = min(t0 + CHUNK, TOTAL_E);
    for (int t = t0 + threadIdx.x; t < t1; t += 256) {
        int row;
        if (t < EAA) {
            row = dst_aa[t];
        } else if (t < EAA + ETA) {
            int u = t - EAA;
            row = NA + dst_ta[u];
            atomicAdd(&srch[50000 + src_ta[u]], 1);
        } else {
            int u = t - EAA - ETA;
            row = 2 * NA + dst_at[u];
            atomicAdd(&srch[src_at[u]], 1);
        }
        atomicAdd(&h[row >> 9], 1);
    }
    __syncthreads();
    // reserve this block's slice of each bucket
    for (int i = threadIdx.x; i < NB; i += 256) {
        int base = atomicAdd(&wi[O_BTOT + i], h[i]);
        wi[O_HIST + i * NBLK1 + b] = base;
    }
}

// ---------- aux: block 0 = 245 bucket scan; blocks 1..74 = src coefs (8-copy sum); block 75 = U fuse ----------
__global__ void __launch_bounds__(1024)
aux_kernel(int* __restrict__ wi, float* __restrict__ wf,
           const float* __restrict__ W2_aa, const float* __restrict__ W2_ta,
           const float* __restrict__ W2_at, const float* __restrict__ b2_aa,
           const float* __restrict__ b2_ta, const float* __restrict__ b2_at,
           const float* __restrict__ Wp_a, const float* __restrict__ bp_a,
           const float* __restrict__ Wp_t, const float* __restrict__ bp_t) {
    if (blockIdx.x == 0) {
        __shared__ int s[NB];
        int t = threadIdx.x;
        if (t < NB) s[t] = wi[O_BTOT + t];
        __syncthreads();
        for (int off = 1; off < NB; off <<= 1) {
            int x = 0;
            if (t < NB && t >= off) x = s[t - off];
            __syncthreads();
            if (t < NB) s[t] += x;
            __syncthreads();
        }
        if (t < NB) wi[O_BBASE + t] = s[t] - wi[O_BTOT + t];   // exclusive
        if (t == 0) wi[O_BBASE + NB] = TOTAL_E;
    } else if (blockIdx.x <= 74) {
        int t = (blockIdx.x - 1) * 1024 + threadIdx.x;
        if (t < 75000) {
            int d = 0;
#pragma unroll
            for (int c = 0; c < 8; ++c) d += wi[O_SRCH + c * SRCH_STRIDE + t];
            float v = d > 0 ? rsqrtf((float)d) : 0.0f;
            if (t < 50000) wf[O_CATS + t] = v;
            else           wf[O_CTAS + (t - 50000)] = v;
        }
    } else {
        float* U = wf + O_U;
        int t = threadIdx.x;
        if (t < 128) {
            int k = t >> 1, j = t & 1;
            float a = 0.f;
            for (int f = 0; f < 64; ++f) a = fmaf(W2_aa[k * 64 + f], Wp_a[f * 2 + j], a);
            U[t] = a;
        } else if (t < 256) {
            int u = t - 128; int k = u >> 1, j = u & 1;
            float a = 0.f;
            for (int f = 0; f < 64; ++f) a = fmaf(W2_ta[k * 64 + f], Wp_a[f * 2 + j], a);
            U[128 + u] = a;
        } else if (t < 384) {
            int u = t - 256; int k = u >> 1, j = u & 1;
            float a = 0.f;
            for (int f = 0; f < 64; ++f) a = fmaf(W2_at[k * 64 + f], Wp_t[f * 2 + j], a);
            U[256 + u] = a;
        } else if (t < 386) {
            int j = t - 384;
            float a = bp_a[j];
            for (int f = 0; f < 64; ++f) a = fmaf(b2_aa[f] + b2_ta[f], Wp_a[f * 2 + j], a);
            U[384 + j] = a;
        } else if (t < 388) {
            int j = t - 386;
            float a = bp_t[j];
            for (int f = 0; f < 64; ++f) a = fmaf(b2_at[f], Wp_t[f * 2 + j], a);
            U[386 + j] = a;
        }
    }
}

// ---------- pass 1c: scatter packed records via LDS cursors (atomic-reserved runs) ----------
__global__ void __launch_bounds__(256)
p1_scatter_kernel(const int* __restrict__ src_aa, const int* __restrict__ dst_aa,
                  const int* __restrict__ src_ta, const int* __restrict__ dst_ta,
                  const int* __restrict__ src_at, const int* __restrict__ dst_at,
                  const int* __restrict__ wi, int* __restrict__ rec) {
    __shared__ int cur[NB];
    int b = blockIdx.x;
    for (int i = threadIdx.x; i < NB; i += 256)
        cur[i] = wi[O_BBASE + i] + wi[O_HIST + i * NBLK1 + b];
    __syncthreads();
    int t0 = b * CHUNK, t1 = min(t0 + CHUNK, TOTAL_E);
    for (int t = t0 + threadIdx.x; t < t1; t += 256) {
        int row, s;
        if (t < EAA) { row = dst_aa[t]; s = src_aa[t]; }
        else if (t < EAA + ETA) { int u = t - EAA; row = NA + dst_ta[u]; s = src_ta[u]; }
        else { int u = t - EAA - ETA; row = 2 * NA + dst_at[u]; s = src_at[u]; }
        int pos = atomicAdd(&cur[row >> 9], 1);
        rec[pos] = ((row & 511) << 16) | s;
    }
}

// ---------- pass 2: per-bucket degree count + LDS scan -> ro + dst coefs + CSR scatter ----------
__global__ void __launch_bounds__(256)
p2_kernel(const int* __restrict__ wi, const int* __restrict__ rec,
          int* __restrict__ ro, float* __restrict__ caa, float* __restrict__ ctad,
          float* __restrict__ catd, unsigned short* __restrict__ csr) {
    __shared__ int deg[512];
    __shared__ int rb[512];
    __shared__ int wsum[4];
    int k = blockIdx.x, tid = threadIdx.x, lane = tid & 63, wid = tid >> 6;
    int e0 = wi[O_BBASE + k];
    int e1 = wi[O_BBASE + k + 1];
    deg[tid] = 0; deg[tid + 256] = 0;
    __syncthreads();
    for (int j = e0 + tid; j < e1; j += 256) atomicAdd(&deg[rec[j] >> 16], 1);
    __syncthreads();
    int d0 = deg[2 * tid], d1 = deg[2 * tid + 1];
    int v = d0 + d1;
    int x = v;
#pragma unroll
    for (int off = 1; off < 64; off <<= 1) {
        int y = __shfl_up(x, off, 64);
        if (lane >= off) x += y;
    }
    if (lane == 63) wsum[wid] = x;
    __syncthreads();
    int wpre = 0;
    for (int w = 0; w < wid; ++w) wpre += wsum[w];
    int pexcl = x - v + wpre;
    rb[2 * tid] = e0 + pexcl;
    rb[2 * tid + 1] = e0 + pexcl + d0;
    __syncthreads();
    for (int i = tid; i < 512; i += 256) {
        int g = k * 512 + i;
        if (g < NSEG) {
            ro[g] = rb[i];
            int d = deg[i];
            if (g < NA) caa[g] = rsqrtf((float)d + 1.0f);
            else if (g < 2 * NA) ctad[g - NA] = d > 0 ? rsqrtf((float)d) : 0.0f;
            else catd[g - 2 * NA] = d > 0 ? rsqrtf((float)d) : 0.0f;
        }
    }
    if (k == NB - 1 && tid == 0) ro[NSEG] = TOTAL_E;
    __syncthreads();
    for (int j = e0 + tid; j < e1; j += 256) {
        int rc = rec[j];
        int pos = atomicAdd(&rb[rc >> 16], 1);
        csr[pos] = (unsigned short)(rc & 0xFFFF);
    }
}

// ---------- conv1: preload+shfl gather + readlane-broadcast matvec (transposed b64 W in LDS) ----------
__global__ void __launch_bounds__(256)
conv1_all_kernel(const float* __restrict__ x_a, const float* __restrict__ x_t,
                 const int* __restrict__ ro, const unsigned short* __restrict__ csr,
                 const float* __restrict__ c_aa, const float* __restrict__ c_ta_d,
                 const float* __restrict__ c_ta_s, const float* __restrict__ c_at_s,
                 const float* __restrict__ c_at_d,
                 const float* __restrict__ W_aa, const float* __restrict__ b_aa,
                 const float* __restrict__ W_ta, const float* __restrict__ b_ta,
                 const float* __restrict__ W_at, const float* __restrict__ b_at,
                 const float* __restrict__ U,
                 float* __restrict__ p, float* __restrict__ q, float* __restrict__ r) {
    __shared__ float sW0[64 * 34];   // transposed: sW0[col*34 + k]
    __shared__ float sW1[64 * 34];
    int lane = threadIdx.x & 63;
    int wave = threadIdx.x >> 6;
    int e8 = lane >> 3, k4 = lane & 7;

    if (blockIdx.x < NA / 4) {
        // ---------- agents ----------
        for (int idx = threadIdx.x; idx < 2048; idx += 256) {
            int k = idx >> 6, col = idx & 63;
            sW0[col * 34 + k] = W_aa[idx];
            sW1[col * 34 + k] = W_ta[idx];
        }
        __syncthreads();
        int i = blockIdx.x * 4 + wave;
        float ci = c_aa[i];
        float bias = b_aa[lane] + b_ta[lane];
        int b0 = ro[i], e0v = ro[i + 1];
        int b1 = ro[NA + i], e1v = ro[NA + i + 1];
        int na = e0v - b0, nt = e1v - b1;
        int sA = (lane < na) ? (int)csr[b0 + lane] : -1;
        int sT = (lane < nt) ? (int)csr[b1 + lane] : -1;

        float4 accA = make_float4(0.f, 0.f, 0.f, 0.f);
        int ngA = min(na, 64);
        for (int g = 0; g * 8 < ngA; ++g) {
            int s = __shfl(sA, g * 8 + e8, 64);
            if (s >= 0) {
                float w = c_aa[s];
                float4 xv = *(const float4*)(x_a + (size_t)s * 32 + k4 * 4);
                accA.x = fmaf(xv.x, w, accA.x);
                accA.y = fmaf(xv.y, w, accA.y);
                accA.z = fmaf(xv.z, w, accA.z);
                accA.w = fmaf(xv.w, w, accA.w);
            }
        }
        for (int j = b0 + 64 + e8; j < e0v; j += 8) {   // rare tail
            int s = csr[j];
            float w = c_aa[s];
            float4 xv = *(const float4*)(x_a + (size_t)s * 32 + k4 * 4);
            accA.x = fmaf(xv.x, w, accA.x);
            accA.y = fmaf(xv.y, w, accA.y);
            accA.z = fmaf(xv.z, w, accA.z);
            accA.w = fmaf(xv.w, w, accA.w);
        }
        if (e8 == 0) {  // self-loop
            float4 xv = *(const float4*)(x_a + (size_t)i * 32 + k4 * 4);
            accA.x = fmaf(xv.x, ci, accA.x);
            accA.y = fmaf(xv.y, ci, accA.y);
            accA.z = fmaf(xv.z, ci, accA.z);
            accA.w = fmaf(xv.w, ci, accA.w);
        }
        float4 accT = make_float4(0.f, 0.f, 0.f, 0.f);
        int ngT = min(nt, 64);
        for (int g = 0; g * 8 < ngT; ++g) {
            int s = __shfl(sT, g * 8 + e8, 64);
            if (s >= 0) {
                float w = c_ta_s[s];
                float4 xv = *(const float4*)(x_t + (size_t)s * 32 + k4 * 4);
                accT.x = fmaf(xv.x, w, accT.x);
                accT.y = fmaf(xv.y, w, accT.y);
                accT.z = fmaf(xv.z, w, accT.z);
                accT.w = fmaf(xv.w, w, accT.w);
            }
        }
        for (int j = b1 + 64 + e8; j < e1v; j += 8) {   // rare tail
            int s = csr[j];
            float w = c_ta_s[s];
            float4 xv = *(const float4*)(x_t + (size_t)s * 32 + k4 * 4);
            accT.x = fmaf(xv.x, w, accT.x);
            accT.y = fmaf(xv.y, w, accT.y);
            accT.z = fmaf(xv.z, w, accT.z);
            accT.w = fmaf(xv.w, w, accT.w);
        }
#pragma unroll
        for (int m = 8; m <= 32; m <<= 1) {
            accA.x += __shfl_xor(accA.x, m, 64);
            accA.y += __shfl_xor(accA.y, m, 64);
            accA.z += __shfl_xor(accA.z, m, 64);
            accA.w += __shfl_xor(accA.w, m, 64);
            accT.x += __shfl_xor(accT.x, m, 64);
            accT.y += __shfl_xor(accT.y, m, 64);
            accT.z += __shfl_xor(accT.z, m, 64);
            accT.w += __shfl_xor(accT.w, m, 64);
        }
        float hA = 0.f, hT = 0.f;
#pragma unroll
        for (int g = 0; g < 8; ++g) {
            float a0 = bcast(accA.x, g), a1 = bcast(accA.y, g);
            float a2 = bcast(accA.z, g), a3 = bcast(accA.w, g);
            float t0 = bcast(accT.x, g), t1 = bcast(accT.y, g);
            float t2 = bcast(accT.z, g), t3 = bcast(accT.w, g);
            float2 wa01 = *(const float2*)&sW0[lane * 34 + g * 4];
            float2 wa23 = *(const float2*)&sW0[lane * 34 + g * 4 + 2];
            float2 wt01 = *(const float2*)&sW1[lane * 34 + g * 4];
            float2 wt23 = *(const float2*)&sW1[lane * 34 + g * 4 + 2];
            hA = fmaf(a0, wa01.x, hA); hA = fmaf(a1, wa01.y, hA);
            hA = fmaf(a2, wa23.x, hA); hA = fmaf(a3, wa23.y, hA);
            hT = fmaf(t0, wt01.x, hT); hT = fmaf(t1, wt01.y, hT);
            hT = fmaf(t2, wt23.x, hT); hT = fmaf(t3, wt23.y, hT);
        }
        float h = fmaxf(bias + ci * hA + c_ta_d[i] * hT, 0.f);
        float p0 = h * U[lane * 2], p1 = h * U[lane * 2 + 1];
        float q0 = h * U[256 + lane * 2], q1 = h * U[256 + lane * 2 + 1];
#pragma unroll
        for (int m = 32; m; m >>= 1) {
            p0 += __shfl_xor(p0, m, 64);
            p1 += __shfl_xor(p1, m, 64);
            q0 += __shfl_xor(q0, m, 64);
            q1 += __shfl_xor(q1, m, 64);
        }
        if (lane == 0) {
            float cq = c_at_s[i];
            *(float2*)&p[i * 2] = make_float2(p0 * ci, p1 * ci);
            *(float2*)&q[i * 2] = make_float2(q0 * cq, q1 * cq);
        }
    } else {
        // ---------- targets ----------
        for (int idx = threadIdx.x; idx < 2048; idx += 256) {
            int k = idx >> 6, col = idx & 63;
            sW0[col * 34 + k] = W_at[idx];
        }
        __syncthreads();
        int i = (blockIdx.x - NA / 4) * 4 + wave;
        float bias = b_at[lane];
        int b0 = ro[2 * NA + i], e0v = ro[2 * NA + i + 1];
        int na = e0v - b0;
        int sA = (lane < na) ? (int)csr[b0 + lane] : -1;
        float4 acc = make_float4(0.f, 0.f, 0.f, 0.f);
        int ng = min(na, 64);
        for (int g = 0; g * 8 < ng; ++g) {
            int s = __shfl(sA, g * 8 + e8, 64);
            if (s >= 0) {
                float w = c_at_s[s];
                float4 xv = *(const float4*)(x_a + (size_t)s * 32 + k4 * 4);
                acc.x = fmaf(xv.x, w, acc.x);
                acc.y = fmaf(xv.y, w, acc.y);
                acc.z = fmaf(xv.z, w, acc.z);
                acc.w = fmaf(xv.w, w, acc.w);
            }
        }
        for (int j = b0 + 64 + e8; j < e0v; j += 8) {   // rare tail
            int s = csr[j];
            float w = c_at_s[s];
            float4 xv = *(const float4*)(x_a + (size_t)s * 32 + k4 * 4);
            acc.x = fmaf(xv.x, w, acc.x);
            acc.y = fmaf(xv.y, w, acc.y);
            acc.z = fmaf(xv.z, w, acc.z);
            acc.w = fmaf(xv.w, w, acc.w);
        }
#pragma unroll
        for (int m = 8; m <= 32; m <<= 1) {
            acc.x += __shfl_xor(acc.x, m, 64);
            acc.y += __shfl_xor(acc.y, m, 64);
            acc.z += __shfl_xor(acc.z, m, 64);
            acc.w += __shfl_xor(acc.w, m, 64);
        }
        float hA = 0.f;
#pragma unroll
        for (int g = 0; g < 8; ++g) {
            float a0 = bcast(acc.x, g), a1 = bcast(acc.y, g);
            float a2 = bcast(acc.z, g), a3 = bcast(acc.w, g);
            float2 w01 = *(const float2*)&sW0[lane * 34 + g * 4];
            float2 w23 = *(const float2*)&sW0[lane * 34 + g * 4 + 2];
            hA = fmaf(a0, w01.x, hA); hA = fmaf(a1, w01.y, hA);
            hA = fmaf(a2, w23.x, hA); hA = fmaf(a3, w23.y, hA);
        }
        float h = fmaxf(bias + c_at_d[i] * hA, 0.f);
        float r0 = h * U[128 + lane * 2], r1 = h * U[128 + lane * 2 + 1];
#pragma unroll
        for (int m = 32; m; m >>= 1) {
            r0 += __shfl_xor(r0, m, 64);
            r1 += __shfl_xor(r1, m, 64);
        }
        if (lane == 0) {
            float cr = c_ta_s[i];
            *(float2*)&r[i * 2] = make_float2(r0 * cr, r1 * cr);
        }
    }
}

// ---------- conv2+proj: one wave per node, 32 edge slots x 2 comps ----------
__global__ void __launch_bounds__(256)
out_all_kernel(const float* __restrict__ p, const float* __restrict__ q,
               const float* __restrict__ r, const int* __restrict__ ro,
               const unsigned short* __restrict__ csr,
               const float* __restrict__ c_aa, const float* __restrict__ c_ta_d,
               const float* __restrict__ c_at_d, const float* __restrict__ U,
               float* __restrict__ out) {
    int wgid = blockIdx.x * 4 + (threadIdx.x >> 6);
    int lane = threadIdx.x & 63;
    int slot = lane >> 1, j = lane & 1;
    if (wgid < NA) {
        int i = wgid;
        int b0 = ro[i], n0 = ro[i + 1] - b0;
        float accA = (slot == 0) ? p[i * 2 + j] : 0.f;   // self-loop (p premultiplied)
        for (int e = slot; e < n0; e += 32) accA += p[(int)csr[b0 + e] * 2 + j];
        int b1 = ro[NA + i], n1 = ro[NA + i + 1] - b1;
        float accT = 0.f;
        for (int e = slot; e < n1; e += 32) accT += r[(int)csr[b1 + e] * 2 + j];
#pragma unroll
        for (int m = 2; m <= 32; m <<= 1) {
            accA += __shfl_xor(accA, m, 64);
            accT += __shfl_xor(accT, m, 64);
        }
        if (lane < 2) out[i * 2 + j] = U[384 + j] + accA * c_aa[i] + accT * c_ta_d[i];
    } else {
        int i = wgid - NA;
        int b0 = ro[2 * NA + i], n0 = ro[2 * NA + i + 1] - b0;
        float acc = 0.f;
        for (int e = slot; e < n0; e += 32) acc += q[(int)csr[b0 + e] * 2 + j];
#pragma unroll
        for (int m = 2; m <= 32; m <<= 1) acc += __shfl_xor(acc, m, 64);
        if (lane < 2) out[NA * 2 + i * 2 + j] = U[386 + j] + acc * c_at_d[i];
    }
}

extern "C" void kernel_launch(void* const* d_in, const int* in_sizes, int n_in,
                              void* d_out, int out_size, void* d_ws, size_t ws_size,
                              hipStream_t stream) {
    const float* x_a   = (const float*)d_in[1];
    const float* x_t   = (const float*)d_in[2];
    const int* src_aa  = (const int*)d_in[3];
    const int* dst_aa  = (const int*)d_in[4];
    const int* src_at  = (const int*)d_in[5];
    const int* dst_at  = (const int*)d_in[6];
    const int* src_ta  = (const int*)d_in[7];
    const int* dst_ta  = (const int*)d_in[8];
    const float* W1_aa = (const float*)d_in[9];
    const float* b1_aa = (const float*)d_in[10];
    const float* W1_at = (const float*)d_in[11];
    const float* b1_at = (const float*)d_in[12];
    const float* W1_ta = (const float*)d_in[13];
    const float* b1_ta = (const float*)d_in[14];
    const float* W2_aa = (const float*)d_in[15];
    const float* b2_aa = (const float*)d_in[16];
    const float* W2_at = (const float*)d_in[17];
    const float* b2_at = (const float*)d_in[18];
    const float* W2_ta = (const float*)d_in[19];
    const float* b2_ta = (const float*)d_in[20];
    const float* Wp_a  = (const float*)d_in[21];
    const float* bp_a  = (const float*)d_in[22];
    const float* Wp_t  = (const float*)d_in[23];
    const float* bp_t  = (const float*)d_in[24];

    int*   wi  = (int*)d_ws;
    float* wf  = (float*)d_ws;
    unsigned short* csr = (unsigned short*)(wi + O_CSR);
    float* out = (float*)d_out;

    // zero the 8-copy src-degree histograms + bucket totals
    hipMemsetAsync(wi + O_SRCH, 0, (size_t)8 * SRCH_STRIDE * 4, stream);
    hipMemsetAsync(wi + O_BTOT, 0, 256 * 4, stream);

    // pass 1: coarse bucket histogram + atomic reservation (+ XCD-local src degrees)
    p1_hist_kernel<<<NBLK1, 256, 0, stream>>>(dst_aa, dst_ta, dst_at, src_ta, src_at, wi);

    // tiny bucket scan + src coefs (8-copy sum) + U fuse in one dispatch
    aux_kernel<<<76, 1024, 0, stream>>>(wi, wf, W2_aa, W2_ta, W2_at, b2_aa, b2_ta, b2_at,
                                        Wp_a, bp_a, Wp_t, bp_t);

    // pass 1c: bucket scatter of packed records
    p1_scatter_kernel<<<NBLK1, 256, 0, stream>>>(src_aa, dst_aa, src_ta, dst_ta,
                                                 src_at, dst_at, wi, wi + O_REC);

    // pass 2: per-bucket -> ro + dst coefs + final CSR
    p2_kernel<<<NB, 256, 0, stream>>>(wi, wi + O_REC, wi + O_RO,
                                      wf + O_CAA, wf + O_CTAD, wf + O_CATD, csr);

    // conv1: preload+shfl gather + readlane matvec
    conv1_all_kernel<<<NA / 4 + NT / 4, 256, 0, stream>>>(
        x_a, x_t, wi + O_RO, csr,
        wf + O_CAA, wf + O_CTAD, wf + O_CTAS, wf + O_CATS, wf + O_CATD,
        W1_aa, b1_aa, W1_ta, b1_ta, W1_at, b1_at, wf + O_U,
        wf + O_P, wf + O_Q, wf + O_R);

    // conv2 + projection, wave per node
    out_all_kernel<<<(NA + NT) / 4, 256, 0, stream>>>(
        wf + O_P, wf + O_Q, wf + O_R, wi + O_RO, csr,
        wf + O_CAA, wf + O_CTAD, wf + O_CATD, wf + O_U, out);
}